// Round 6
// baseline (1354.289 us; speedup 1.0000x reference)
//
#include <hip/hip_runtime.h>
#include <hip/hip_bf16.h>
#include <math.h>

#define N_NODES  100000
#define N_EDGES  1600000
#define N_GRAPHS 1024

typedef __hip_bfloat16 bf16;
typedef unsigned short u16;
typedef unsigned int   u32;
typedef __attribute__((ext_vector_type(8))) short bf8_t;   // 8 bf16 (4 VGPRs)
typedef __attribute__((ext_vector_type(4))) float f4_t;    // 4 fp32 acc

__device__ __forceinline__ float b2f(bf16 v) { return __bfloat162float(v); }
__device__ __forceinline__ u16 bfbits(float f) {
    bf16 h = __float2bfloat16(f);
    return *reinterpret_cast<u16*>(&h);
}
__device__ __forceinline__ float lo_bf(u32 u) { return __uint_as_float(u << 16); }
__device__ __forceinline__ float hi_bf(u32 u) { return __uint_as_float(u & 0xffff0000u); }

// ---------------- dtype sniff: flag=1 if external float tensors are bf16 ----
__global__ void sniff_dtype(const u16* __restrict__ p, int* __restrict__ flag) {
    if (blockIdx.x == 0 && threadIdx.x == 0) {
        int bad = 0;
        for (int i = 0; i < 256; ++i) {
            float f = __uint_as_float(((u32)p[i]) << 16);
            if (!(fabsf(f) < 100.f)) bad++;
        }
        *flag = (bad == 0) ? 1 : 0;
    }
}

// ---------------- fused weight prep: cvt->fp32 or repack->MFMA bf16 -------
#define NT 18
struct WTask { const void* src; void* dst; int n; int mode; int K; };
struct PrepArgs { WTask t[NT]; int bstart[NT]; };

__global__ void prep_k(PrepArgs args, const int* __restrict__ flag) {
    int b = blockIdx.x, ti = 0;
    while (ti < NT - 1 && b >= args.bstart[ti + 1]) ++ti;
    int idx = (b - args.bstart[ti]) * 256 + threadIdx.x;
    WTask tk = args.t[ti];
    if (idx >= tk.n) return;
    int isb = *flag;
    if (tk.mode == 0) {
        float v = isb ? b2f(((const bf16*)tk.src)[idx]) : ((const float*)tk.src)[idx];
        ((float*)tk.dst)[idx] = v;
    } else {
        // MFMA B-frag layout: element = W[kb*32+(L>>4)*8+j][t*16+(L&15)]
        int bseg = idx >> 9, r = idx & 511;
        int L = r >> 3, j = r & 7;
        int kb = bseg >> 3, tt = bseg & 7;
        int k = kb * 32 + ((L >> 4) << 3) + j;
        int n = (tt << 4) + (L & 15);
        int so = k * 128 + n;
        float v = isb ? b2f(((const bf16*)tk.src)[so]) : ((const float*)tk.src)[so];
        ((u16*)tk.dst)[idx] = bfbits(v);
    }
}

// ---------------- x_graph -> bf16 chunk-major [4][N][16] ----------------
__global__ void cvt_xc(const void* __restrict__ src, u16* __restrict__ dst,
                       const int* __restrict__ flag) {
    int i = blockIdx.x * blockDim.x + threadIdx.x;   // over N*64
    if (i >= N_NODES * 64) return;
    int node = i >> 6, f = i & 63;
    u16 v;
    if (*flag) v = ((const u16*)src)[i];
    else       v = bfbits(((const float*)src)[i]);
    dst[((size_t)(f >> 4) * N_NODES + node) * 16 + (f & 15)] = v;
}

// ---------------- degree / norm ----------------
__global__ void deg_init(int* degi) {
    int i = blockIdx.x * blockDim.x + threadIdx.x;
    if (i < N_NODES) degi[i] = 2;
}

__global__ void deg_edges(const int* __restrict__ dst, int* __restrict__ degi) {
    int e = blockIdx.x * blockDim.x + threadIdx.x;
    if (e < N_EDGES) atomicAdd(&degi[dst[e]], 1);
}

__global__ void dinv_k(const int* __restrict__ degi, float* __restrict__ dinv) {
    int i = blockIdx.x * blockDim.x + threadIdx.x;
    if (i < N_NODES) dinv[i] = rsqrtf((float)degi[i]);
}

// ---------------- CSR build ----------------
#define SCAN_B 256
__global__ void scan1(const int* __restrict__ degi, int* __restrict__ ex,
                      int* __restrict__ bsum) {
    __shared__ int s[SCAN_B];
    int i = blockIdx.x * SCAN_B + threadIdx.x;
    int v = (i < N_NODES) ? (degi[i] - 2) : 0;
    s[threadIdx.x] = v;
    __syncthreads();
    for (int off = 1; off < SCAN_B; off <<= 1) {
        int t = (threadIdx.x >= off) ? s[threadIdx.x - off] : 0;
        __syncthreads();
        if (threadIdx.x >= off) s[threadIdx.x] += t;
        __syncthreads();
    }
    if (i < N_NODES) ex[i] = s[threadIdx.x] - v;
    if (threadIdx.x == SCAN_B - 1) bsum[blockIdx.x] = s[SCAN_B - 1];
}

__global__ void scan2(int* __restrict__ bsum, int nb) {
    __shared__ int s[512];
    int i = threadIdx.x;
    int v = (i < nb) ? bsum[i] : 0;
    s[i] = v;
    __syncthreads();
    for (int off = 1; off < 512; off <<= 1) {
        int t = (i >= off) ? s[i - off] : 0;
        __syncthreads();
        if (i >= off) s[i] += t;
        __syncthreads();
    }
    if (i < nb) bsum[i] = s[i] - v;   // exclusive
}

__global__ void scan3(int* __restrict__ rowptr, const int* __restrict__ bsum,
                      int* __restrict__ cnt) {
    int i = blockIdx.x * SCAN_B + threadIdx.x;
    if (i >= N_NODES) return;
    rowptr[i] += bsum[blockIdx.x];
    cnt[i] = 0;
}

// packed 4B CSR entry: (q15(dinv_src) << 17) | src
__global__ void fill_csr(const int* __restrict__ src, const int* __restrict__ dst,
                         const float* __restrict__ dinv, const int* __restrict__ rowptr,
                         int* __restrict__ cnt, u32* __restrict__ csr4) {
    int e = blockIdx.x * 256 + threadIdx.x;
    if (e >= N_EDGES) return;
    int s = src[e], d = dst[e];
    int pos = rowptr[d] + atomicAdd(&cnt[d], 1);
    u32 q = (u32)__float2int_rn(dinv[s] * 32767.f);
    csr4[pos] = (q << 17) | (u32)s;
}

// ---------------- MFMA GEMM: Out[chunk-major] = A[chunk-major] @ W ----
// A layout: [K/16][N][16] bf16; Out layout: [8][N][16] bf16
// block = 4 waves x 16 rows = 64 rows; per wave: 8 n-tiles of 16
template<int K, bool EPI>
__global__ __launch_bounds__(256) void gemm_mfma(const u16* __restrict__ A,
        const u16* __restrict__ Wm, const float* __restrict__ bias,
        u16* __restrict__ Out, int M)
{
    int wave = threadIdx.x >> 6, lane = threadIdx.x & 63;
    int rowBase = blockIdx.x * 64 + wave * 16;
    int quad = lane >> 4, low = lane & 15;
    int arow = rowBase + low;
    if (arow >= M) arow = M - 1;

    f4_t acc[8];
#pragma unroll
    for (int t = 0; t < 8; ++t) acc[t] = (f4_t)(0.f);

#pragma unroll
    for (int kb = 0; kb < K / 32; ++kb) {
        const u16* ap = A + ((size_t)((kb << 1) + (quad >> 1)) * N_NODES + arow) * 16
                          + ((quad & 1) << 3);
        bf8_t a = *(const bf8_t*)ap;
#pragma unroll
        for (int t = 0; t < 8; ++t) {
            bf8_t b = *(const bf8_t*)(Wm + (((kb << 3) + t) << 9) + lane * 8);
            acc[t] = __builtin_amdgcn_mfma_f32_16x16x32_bf16(a, b, acc[t], 0, 0, 0);
        }
    }

    int orow0 = rowBase + quad * 4;
#pragma unroll
    for (int t = 0; t < 8; ++t) {
        float bn = EPI ? bias[t * 16 + low] : 0.f;
#pragma unroll
        for (int j = 0; j < 4; ++j) {
            int r = orow0 + j;
            float v = acc[t][j];
            if (EPI) v = fmaxf(v + bn, 0.f);
            if (r < M) Out[((size_t)t * N_NODES + r) * 16 + low] = bfbits(v);
        }
    }
}

// ---------------- chunked gather: per (node, chunk) ----------------
// A[d] = [relu](bias + dinv_d * (2*dinv_d*H[d] + sum_e q_s*H[s]))
// chunk = blockIdx & (NCH-1)  -> XCD-pinned 16-feature panel (3.2MB, L2-resident)
// wave per node: 8 edge-slots x 8 u32 features; shfl_xor reduce over slots
template<int CBITS, bool EPI>
__global__ __launch_bounds__(512) void gather_c(
        const int* __restrict__ rowptr, const int* __restrict__ cnt,
        const u32* __restrict__ csr4, const u16* __restrict__ Hc,
        const float* __restrict__ dinv, const float* __restrict__ bias,
        u16* __restrict__ Ac)
{
    const int NCH = 1 << CBITS;
    int chunk = blockIdx.x & (NCH - 1);
    int node = (blockIdx.x >> CBITS) * 8 + (threadIdx.x >> 6);
    if (node >= N_NODES) return;
    int lane = threadIdx.x & 63;
    int es = lane >> 3, fi = lane & 7;
    const u32* Hrow = (const u32*)Hc + (size_t)chunk * N_NODES * 8;
    float dv = dinv[node];
    float accx = 0.f, accy = 0.f;
    if (es == 0) {
        u32 h = Hrow[(size_t)node * 8 + fi];
        float w = 2.f * dv;
        accx = w * lo_bf(h); accy = w * hi_bf(h);
    }
    int rp = rowptr[node];
    int end = rp + cnt[node];
    for (int p = rp + es; p < end; p += 8) {
        u32 m = csr4[p];
        int s = (int)(m & 0x1FFFFu);
        float w = (float)(m >> 17) * (1.f / 32767.f);
        u32 h = Hrow[(size_t)s * 8 + fi];
        accx += w * lo_bf(h);
        accy += w * hi_bf(h);
    }
    accx += __shfl_xor(accx, 8);  accy += __shfl_xor(accy, 8);
    accx += __shfl_xor(accx, 16); accy += __shfl_xor(accy, 16);
    accx += __shfl_xor(accx, 32); accy += __shfl_xor(accy, 32);
    if (es == 0) {
        accx *= dv; accy *= dv;
        if (EPI) {
            float2 bb = ((const float2*)bias)[chunk * 8 + fi];
            accx = fmaxf(accx + bb.x, 0.f);
            accy = fmaxf(accy + bb.y, 0.f);
        }
        u32 pack = ((u32)bfbits(accy) << 16) | (u32)bfbits(accx);
        ((u32*)Ac)[((size_t)chunk * N_NODES + node) * 8 + fi] = pack;
    }
}

// ---------------- per-graph mean/max pooling (batch sorted, chunk-major A) --
__global__ __launch_bounds__(128) void pool_k(const u16* __restrict__ A,
        const int* __restrict__ batch, float* __restrict__ concat)
{
    __shared__ int sb[2];
    int g = blockIdx.x;
    if (threadIdx.x == 0) {
        int lo = 0, hi = N_NODES;
        while (lo < hi) { int m = (lo + hi) >> 1; if (batch[m] < g) lo = m + 1; else hi = m; }
        sb[0] = lo;
        hi = N_NODES;
        while (lo < hi) { int m = (lo + hi) >> 1; if (batch[m] < g + 1) lo = m + 1; else hi = m; }
        sb[1] = lo;
    }
    __syncthreads();
    int start = sb[0], end = sb[1];
    int t = threadIdx.x;
    const u16* Ap = A + (size_t)(t >> 4) * N_NODES * 16 + (t & 15);
    float sum = 0.f, mx = -3.4e38f;
    for (int n = start; n < end; ++n) {
        float v = __uint_as_float(((u32)Ap[(size_t)n * 16]) << 16);
        sum += v; mx = fmaxf(mx, v);
    }
    int cnt = end - start;
    float mean = sum / (float)(cnt > 0 ? cnt : 1);
    if (cnt == 0) mx = 0.f;
    concat[g * 384 + t] = mean;
    concat[g * 384 + 128 + t] = mx;
}

// ---------------- small row GEMM (fp32 head) ----------------
template<int KD, bool EXT>
__global__ void rowmm(const void* __restrict__ Xv, int ldx,
                      const float* __restrict__ W, const float* __restrict__ bias,
                      float* __restrict__ out, int ldo, const int* __restrict__ flagp)
{
    extern __shared__ float xs[];
    int g = blockIdx.x;
    int col = threadIdx.x;
    int N = blockDim.x;
    const int isb = EXT ? *flagp : 0;
    for (int k = col; k < KD; k += N) {
        size_t off = (size_t)g * ldx + k;
        xs[k] = EXT ? (isb ? b2f(((const bf16*)Xv)[off]) : ((const float*)Xv)[off])
                    : ((const float*)Xv)[off];
    }
    __syncthreads();
    float acc = bias[col];
    for (int k = 0; k < KD; ++k)
        acc += xs[k] * W[(size_t)k * N + col];
    out[(size_t)g * ldo + col] = fmaxf(acc, 0.f);
}

// ---------------- final dot + sigmoid ----------------
__global__ __launch_bounds__(256) void head3(const float* __restrict__ u2,
        const float* __restrict__ Wf3, const float* __restrict__ bf3,
        void* __restrict__ out, const int* __restrict__ flagp)
{
    int g = blockIdx.x * 4 + (threadIdx.x >> 6);
    int lane = threadIdx.x & 63;
    float2 v = ((const float2*)(u2 + (size_t)g * 128))[lane];
    float2 w = ((const float2*)Wf3)[lane];
    float acc = v.x * w.x + v.y * w.y;
    for (int off = 32; off > 0; off >>= 1) acc += __shfl_down(acc, off);
    if (lane == 0) {
        float z = acc + bf3[0];
        float sg = 1.f / (1.f + expf(-z));
        if (*flagp) ((bf16*)out)[g] = __float2bfloat16(sg);
        else        ((float*)out)[g] = sg;
    }
}

extern "C" void kernel_launch(void* const* d_in, const int* in_sizes, int n_in,
                              void* d_out, int out_size, void* d_ws, size_t ws_size,
                              hipStream_t stream) {
    const void* x_graph    = d_in[0];
    const int*  edge_index = (const int*)d_in[1];
    const int*  batch      = (const int*)d_in[2];
    const void* x_tab      = d_in[3];

    const int* src  = edge_index;
    const int* dstp = edge_index + N_EDGES;

    // ---------------- workspace layout ----------------
    char* wsp = (char*)d_ws;
    int*  flag = (int*)wsp;                      wsp += 16;
    u16*  A16  = (u16*)wsp;                      wsp += (size_t)N_NODES * 128 * 2;  // [8][N][16]
    u16*  B16  = (u16*)wsp;                      wsp += (size_t)N_NODES * 128 * 2;  // [8][N][16]
    u16*  X16  = (u16*)wsp;                      wsp += (size_t)N_NODES * 64 * 2;   // [4][N][16]
    u16*  G16  = (u16*)wsp;                      wsp += (size_t)N_NODES * 64 * 2;   // [4][N][16]
    u16*  Wm[4];
    Wm[0] = (u16*)wsp;                           wsp += 64 * 128 * 2;
    Wm[1] = (u16*)wsp;                           wsp += 128 * 128 * 2;
    Wm[2] = (u16*)wsp;                           wsp += 128 * 128 * 2;
    Wm[3] = (u16*)wsp;                           wsp += 128 * 128 * 2;
    float* p = (float*)wsp;
    float* bg1f = p; p += 128;
    float* bg2f = p; p += 128;
    float* bg3f = p; p += 128;
    float* bg4f = p; p += 128;
    float* Wt1f = p; p += 200 * 256; float* bt1f = p; p += 256;
    float* Wt2f = p; p += 256 * 128; float* bt2f = p; p += 128;
    float* Wf1f = p; p += 384 * 256; float* bf1f = p; p += 256;
    float* Wf2f = p; p += 256 * 128; float* bf2f = p; p += 128;
    float* Wf3f = p; p += 128;       float* bf3f = p; p += 4;
    int*   degi   = (int*)p;            p += N_NODES;
    float* dinv   = p;                  p += N_NODES;
    int*   rowptr = (int*)p;            p += N_NODES;
    int*   cnt    = (int*)p;            p += N_NODES;
    int*   bsum   = (int*)p;            p += 512;
    u32*   csr4   = (u32*)p;            p += N_EDGES;
    float* concat = p;                  p += N_GRAPHS * 384;
    float* t1     = p;                  p += N_GRAPHS * 256;
    float* u1     = p;                  p += N_GRAPHS * 256;
    float* u2     = p;                  p += N_GRAPHS * 128;

    // ---------------- dtype sniff + fused weight prep ----------------
    sniff_dtype<<<1, 64, 0, stream>>>((const u16*)x_graph, flag);

    PrepArgs pa;
    auto setT = [&](int i, const void* s, void* d, int n, int mode, int K) {
        pa.t[i].src = s; pa.t[i].dst = d; pa.t[i].n = n; pa.t[i].mode = mode; pa.t[i].K = K;
    };
    setT(0,  d_in[4],  Wm[0], 64 * 128, 1, 64);
    setT(1,  d_in[6],  Wm[1], 128 * 128, 1, 128);
    setT(2,  d_in[8],  Wm[2], 128 * 128, 1, 128);
    setT(3,  d_in[10], Wm[3], 128 * 128, 1, 128);
    setT(4,  d_in[12], Wt1f, 200 * 256, 0, 0);
    setT(5,  d_in[14], Wt2f, 256 * 128, 0, 0);
    setT(6,  d_in[16], Wf1f, 384 * 256, 0, 0);
    setT(7,  d_in[18], Wf2f, 256 * 128, 0, 0);
    setT(8,  d_in[20], Wf3f, 128, 0, 0);
    setT(9,  d_in[5],  bg1f, 128, 0, 0);
    setT(10, d_in[7],  bg2f, 128, 0, 0);
    setT(11, d_in[9],  bg3f, 128, 0, 0);
    setT(12, d_in[11], bg4f, 128, 0, 0);
    setT(13, d_in[13], bt1f, 256, 0, 0);
    setT(14, d_in[15], bt2f, 128, 0, 0);
    setT(15, d_in[17], bf1f, 256, 0, 0);
    setT(16, d_in[19], bf2f, 128, 0, 0);
    setT(17, d_in[21], bf3f, 1, 0, 0);
    int totalBlocks = 0;
    for (int i = 0; i < NT; ++i) {
        pa.bstart[i] = totalBlocks;
        totalBlocks += (pa.t[i].n + 255) / 256;
    }
    prep_k<<<totalBlocks, 256, 0, stream>>>(pa, flag);
    cvt_xc<<<(N_NODES * 64 + 255) / 256, 256, 0, stream>>>(x_graph, X16, flag);

    // ---------------- degree / norm / CSR ----------------
    const int nb = (N_NODES + SCAN_B - 1) / SCAN_B;   // 391
    deg_init<<<(N_NODES + 255) / 256, 256, 0, stream>>>(degi);
    deg_edges<<<(N_EDGES + 255) / 256, 256, 0, stream>>>(dstp, degi);
    dinv_k<<<(N_NODES + 255) / 256, 256, 0, stream>>>(degi, dinv);
    scan1<<<nb, SCAN_B, 0, stream>>>(degi, rowptr, bsum);
    scan2<<<1, 512, 0, stream>>>(bsum, nb);
    scan3<<<nb, SCAN_B, 0, stream>>>(rowptr, bsum, cnt);
    fill_csr<<<(N_EDGES + 255) / 256, 256, 0, stream>>>(src, dstp, dinv, rowptr, cnt, csr4);

    const int gemmGrid = (N_NODES + 63) / 64;         // 1563
    const int ggrid8   = ((N_NODES + 7) / 8) * 8;     // 100000 (8 chunks)
    const int ggrid4   = ((N_NODES + 7) / 8) * 4;     // 50000  (4 chunks)

    // ---- layer 1 (reassociated): G = A_hat X ; A = relu(G W1 + b1) ----
    gather_c<2, false><<<ggrid4, 512, 0, stream>>>(rowptr, cnt, csr4, X16, dinv, nullptr, G16);
    gemm_mfma<64, true><<<gemmGrid, 256, 0, stream>>>(G16, Wm[0], bg1f, A16, N_NODES);

    // ---- layers 2-4: B = A W_l ; A = relu(agg(B) + b_l) ----
    const float* bgL[4] = {bg1f, bg2f, bg3f, bg4f};
    for (int l = 1; l < 4; ++l) {
        gemm_mfma<128, false><<<gemmGrid, 256, 0, stream>>>(A16, Wm[l], nullptr, B16, N_NODES);
        gather_c<3, true><<<ggrid8, 512, 0, stream>>>(rowptr, cnt, csr4, B16, dinv, bgL[l], A16);
    }

    // pooling -> concat[:, 0:256]
    pool_k<<<N_GRAPHS, 128, 0, stream>>>(A16, batch, concat);

    // tabular branch -> concat[:, 256:384]
    rowmm<200, true><<<N_GRAPHS, 256, 200 * 4, stream>>>(x_tab, 200, Wt1f, bt1f, t1, 256, flag);
    rowmm<256, false><<<N_GRAPHS, 128, 256 * 4, stream>>>(t1, 256, Wt2f, bt2f, concat + 256, 384, flag);

    // fused head
    rowmm<384, false><<<N_GRAPHS, 256, 384 * 4, stream>>>(concat, 384, Wf1f, bf1f, u1, 256, flag);
    rowmm<256, false><<<N_GRAPHS, 128, 256 * 4, stream>>>(u1, 256, Wf2f, bf2f, u2, 128, flag);
    head3<<<N_GRAPHS / 4, 256, 0, stream>>>(u2, Wf3f, bf3f, d_out, flag);
}

// Round 7
// 733.387 us; speedup vs baseline: 1.8466x; 1.8466x over previous
//
#include <hip/hip_runtime.h>
#include <hip/hip_bf16.h>
#include <math.h>

#define N_NODES  100000
#define N_EDGES  1600000
#define N_GRAPHS 1024

typedef __hip_bfloat16 bf16;
typedef unsigned short u16;
typedef unsigned int   u32;
typedef __attribute__((ext_vector_type(8))) short bf8_t;   // 8 bf16 (4 VGPRs)
typedef __attribute__((ext_vector_type(4))) float f4_t;    // 4 fp32 acc

__device__ __forceinline__ float b2f(bf16 v) { return __bfloat162float(v); }
__device__ __forceinline__ u16 bfbits(float f) {
    bf16 h = __float2bfloat16(f);
    return *reinterpret_cast<u16*>(&h);
}
__device__ __forceinline__ float lo_bf(u32 u) { return __uint_as_float(u << 16); }
__device__ __forceinline__ float hi_bf(u32 u) { return __uint_as_float(u & 0xffff0000u); }

// ---------------- sniff dtype + init degi ----------------
__global__ void sniff_init(const u16* __restrict__ xg, int* __restrict__ flag,
                           int* __restrict__ degi) {
    int i = blockIdx.x * 256 + threadIdx.x;
    if (i < N_NODES) degi[i] = 2;   // two self-loop copies per node
    if (blockIdx.x == 0 && threadIdx.x == 0) {
        int bad = 0;
        for (int k = 0; k < 256; ++k) {
            float f = __uint_as_float(((u32)xg[k]) << 16);
            if (!(fabsf(f) < 100.f)) bad++;
        }
        *flag = (bad == 0) ? 1 : 0;
    }
}

// ---------------- fused prep: cvt->fp32 / repack->MFMA bf16 / cvt->bf16 ---
#define NT 19
struct WTask { const void* src; void* dst; int n; int mode; };
struct PrepArgs { WTask t[NT]; int bstart[NT]; };

__global__ void prep_k(PrepArgs args, const int* __restrict__ flag) {
    int b = blockIdx.x, ti = 0;
    while (ti < NT - 1 && b >= args.bstart[ti + 1]) ++ti;
    int idx = (b - args.bstart[ti]) * 256 + threadIdx.x;
    WTask tk = args.t[ti];
    if (idx >= tk.n) return;
    int isb = *flag;
    if (tk.mode == 0) {
        float v = isb ? b2f(((const bf16*)tk.src)[idx]) : ((const float*)tk.src)[idx];
        ((float*)tk.dst)[idx] = v;
    } else if (tk.mode == 1) {
        // MFMA B-frag layout: element = W[kb*32+(L>>4)*8+j][t*16+(L&15)]
        int bseg = idx >> 9, r = idx & 511;
        int L = r >> 3, j = r & 7;
        int kb = bseg >> 3, tt = bseg & 7;
        int k = kb * 32 + ((L >> 4) << 3) + j;
        int n = (tt << 4) + (L & 15);
        int so = k * 128 + n;
        float v = isb ? b2f(((const bf16*)tk.src)[so]) : ((const float*)tk.src)[so];
        ((u16*)tk.dst)[idx] = bfbits(v);
    } else {
        // plain bf16 copy (row-major)
        u16 v = isb ? ((const u16*)tk.src)[idx] : bfbits(((const float*)tk.src)[idx]);
        ((u16*)tk.dst)[idx] = v;
    }
}

// ---------------- degree ----------------
__global__ void deg_edges(const int* __restrict__ dst, int* __restrict__ degi) {
    int e = blockIdx.x * blockDim.x + threadIdx.x;
    if (e < N_EDGES) atomicAdd(&degi[dst[e]], 1);
}

// ---------------- CSR build ----------------
#define SCAN_B 256
__global__ void scan1(const int* __restrict__ degi, int* __restrict__ ex,
                      int* __restrict__ bsum, float* __restrict__ dinv) {
    __shared__ int s[SCAN_B];
    int i = blockIdx.x * SCAN_B + threadIdx.x;
    int dg = (i < N_NODES) ? degi[i] : 2;
    int v = dg - 2;
    s[threadIdx.x] = v;
    __syncthreads();
    for (int off = 1; off < SCAN_B; off <<= 1) {
        int t = (threadIdx.x >= off) ? s[threadIdx.x - off] : 0;
        __syncthreads();
        if (threadIdx.x >= off) s[threadIdx.x] += t;
        __syncthreads();
    }
    if (i < N_NODES) {
        ex[i] = s[threadIdx.x] - v;
        dinv[i] = rsqrtf((float)dg);
    }
    if (threadIdx.x == SCAN_B - 1) bsum[blockIdx.x] = s[SCAN_B - 1];
}

__global__ void scan2(int* __restrict__ bsum, int nb) {
    __shared__ int s[512];
    int i = threadIdx.x;
    int v = (i < nb) ? bsum[i] : 0;
    s[i] = v;
    __syncthreads();
    for (int off = 1; off < 512; off <<= 1) {
        int t = (i >= off) ? s[i - off] : 0;
        __syncthreads();
        if (i >= off) s[i] += t;
        __syncthreads();
    }
    if (i < nb) bsum[i] = s[i] - v;   // exclusive
}

__global__ void scan3(int* __restrict__ rowptr, const int* __restrict__ bsum,
                      int* __restrict__ cnt) {
    int i = blockIdx.x * SCAN_B + threadIdx.x;
    if (i >= N_NODES) return;
    rowptr[i] += bsum[blockIdx.x];
    cnt[i] = 0;
}

// packed 4B CSR entry: (q15(dinv_src) << 17) | src   (dst's dinv factored out)
__global__ void fill_csr(const int* __restrict__ src, const int* __restrict__ dst,
                         const float* __restrict__ dinv, const int* __restrict__ rowptr,
                         int* __restrict__ cnt, u32* __restrict__ csr4) {
    int e = blockIdx.x * 256 + threadIdx.x;
    if (e >= N_EDGES) return;
    int s = src[e], d = dst[e];
    int pos = rowptr[d] + atomicAdd(&cnt[d], 1);
    u32 q = (u32)__float2int_rn(dinv[s] * 32767.f);
    csr4[pos] = (q << 17) | (u32)s;
}

// ---------------- MFMA GEMM: Out[M x 128](bf16) = A[M x K](bf16) @ W ----
// block = 4 waves x 16 rows = 64 rows; per wave: 8 n-tiles of 16
template<int K, bool EPI>
__global__ __launch_bounds__(256) void gemm_mfma(const u16* __restrict__ A,
        const u16* __restrict__ Wm, const float* __restrict__ bias,
        u16* __restrict__ Out, int M)
{
    int wave = threadIdx.x >> 6, lane = threadIdx.x & 63;
    int rowBase = blockIdx.x * 64 + wave * 16;
    int quad = lane >> 4, low = lane & 15;
    int arow = rowBase + low;
    if (arow >= M) arow = M - 1;
    const u16* ap = A + (size_t)arow * K + quad * 8;

    f4_t acc[8];
#pragma unroll
    for (int t = 0; t < 8; ++t) acc[t] = (f4_t)(0.f);

#pragma unroll
    for (int kb = 0; kb < K / 32; ++kb) {
        bf8_t a = *(const bf8_t*)(ap + kb * 32);
#pragma unroll
        for (int t = 0; t < 8; ++t) {
            bf8_t b = *(const bf8_t*)(Wm + (((kb << 3) + t) << 9) + lane * 8);
            acc[t] = __builtin_amdgcn_mfma_f32_16x16x32_bf16(a, b, acc[t], 0, 0, 0);
        }
    }

    int orow0 = rowBase + quad * 4;
#pragma unroll
    for (int t = 0; t < 8; ++t) {
        float bn = EPI ? bias[t * 16 + low] : 0.f;
#pragma unroll
        for (int j = 0; j < 4; ++j) {
            int r = orow0 + j;
            float v = acc[t][j];
            if (EPI) v = fmaxf(v + bn, 0.f);
            if (r < M) Out[(size_t)r * 128 + t * 16 + low] = bfbits(v);
        }
    }
}

// ---------------- gather (128-wide H): A = relu(b + dinv_d*(2*dinv_d*H[d] + sum q_s*H[s])) ----
// one wave per node, 64 lanes x u32 (2 bf16)
__global__ __launch_bounds__(256) void gather_agg(
        const int* __restrict__ rowptr, const int* __restrict__ cnt,
        const u32* __restrict__ csr4, const u16* __restrict__ H,
        const float* __restrict__ dinv, const float* __restrict__ bias,
        u16* __restrict__ A)
{
    int node = blockIdx.x * 4 + (threadIdx.x >> 6);
    if (node >= N_NODES) return;
    int lane = threadIdx.x & 63;
    const u32* H2 = (const u32*)H;
    float2 bb = ((const float2*)bias)[lane];
    float dv = dinv[node];
    u32 h0 = H2[(size_t)node * 64 + lane];
    float accx = 2.f * dv * lo_bf(h0);
    float accy = 2.f * dv * hi_bf(h0);
    int p = rowptr[node];
    int end = p + cnt[node];
    const float qs = 1.f / 32767.f;
    for (; p + 8 <= end; p += 8) {
        u32 m0 = csr4[p],     m1 = csr4[p + 1];
        u32 m2 = csr4[p + 2], m3 = csr4[p + 3];
        u32 m4 = csr4[p + 4], m5 = csr4[p + 5];
        u32 m6 = csr4[p + 6], m7 = csr4[p + 7];
        u32 v0 = H2[(size_t)(m0 & 0x1FFFFu) * 64 + lane];
        u32 v1 = H2[(size_t)(m1 & 0x1FFFFu) * 64 + lane];
        u32 v2 = H2[(size_t)(m2 & 0x1FFFFu) * 64 + lane];
        u32 v3 = H2[(size_t)(m3 & 0x1FFFFu) * 64 + lane];
        u32 v4 = H2[(size_t)(m4 & 0x1FFFFu) * 64 + lane];
        u32 v5 = H2[(size_t)(m5 & 0x1FFFFu) * 64 + lane];
        u32 v6 = H2[(size_t)(m6 & 0x1FFFFu) * 64 + lane];
        u32 v7 = H2[(size_t)(m7 & 0x1FFFFu) * 64 + lane];
        float w0 = (float)(m0 >> 17) * qs, w1 = (float)(m1 >> 17) * qs;
        float w2 = (float)(m2 >> 17) * qs, w3 = (float)(m3 >> 17) * qs;
        float w4 = (float)(m4 >> 17) * qs, w5 = (float)(m5 >> 17) * qs;
        float w6 = (float)(m6 >> 17) * qs, w7 = (float)(m7 >> 17) * qs;
        accx += w0 * lo_bf(v0) + w1 * lo_bf(v1) + w2 * lo_bf(v2) + w3 * lo_bf(v3)
              + w4 * lo_bf(v4) + w5 * lo_bf(v5) + w6 * lo_bf(v6) + w7 * lo_bf(v7);
        accy += w0 * hi_bf(v0) + w1 * hi_bf(v1) + w2 * hi_bf(v2) + w3 * hi_bf(v3)
              + w4 * hi_bf(v4) + w5 * hi_bf(v5) + w6 * hi_bf(v6) + w7 * hi_bf(v7);
    }
    for (; p < end; ++p) {
        u32 m = csr4[p];
        u32 v = H2[(size_t)(m & 0x1FFFFu) * 64 + lane];
        float w = (float)(m >> 17) * qs;
        accx += w * lo_bf(v); accy += w * hi_bf(v);
    }
    accx = fmaxf(accx * dv + bb.x, 0.f);
    accy = fmaxf(accy * dv + bb.y, 0.f);
    u32 pack = ((u32)bfbits(accy) << 16) | (u32)bfbits(accx);
    ((u32*)A)[(size_t)node * 64 + lane] = pack;
}

// ---------------- layer-1 gather on 64-wide X: G = dinv_d*(2*dinv_d*X[d] + sum q_s*X[s]) ----
// one wave per node; half-wave per edge (2 edges in flight)
__global__ __launch_bounds__(256) void gather_x(
        const int* __restrict__ rowptr, const int* __restrict__ cnt,
        const u32* __restrict__ csr4, const u16* __restrict__ X,
        const float* __restrict__ dinv, u16* __restrict__ G)
{
    int node = blockIdx.x * 4 + (threadIdx.x >> 6);
    if (node >= N_NODES) return;
    int lane = threadIdx.x & 63;
    int half = lane >> 5, fi = lane & 31;
    const u32* X2 = (const u32*)X;   // 32 u32 per row
    float dv = dinv[node];
    float accx = 0.f, accy = 0.f;
    if (half == 0) {
        u32 h0 = X2[(size_t)node * 32 + fi];
        accx = 2.f * dv * lo_bf(h0); accy = 2.f * dv * hi_bf(h0);
    }
    int rp = rowptr[node];
    int end = rp + cnt[node];
    const float qs = 1.f / 32767.f;
    int p = rp + half;
    for (; p + 6 < end; p += 8) {
        u32 m0 = csr4[p],     m1 = csr4[p + 2];
        u32 m2 = csr4[p + 4], m3 = csr4[p + 6];
        u32 v0 = X2[(size_t)(m0 & 0x1FFFFu) * 32 + fi];
        u32 v1 = X2[(size_t)(m1 & 0x1FFFFu) * 32 + fi];
        u32 v2 = X2[(size_t)(m2 & 0x1FFFFu) * 32 + fi];
        u32 v3 = X2[(size_t)(m3 & 0x1FFFFu) * 32 + fi];
        float w0 = (float)(m0 >> 17) * qs, w1 = (float)(m1 >> 17) * qs;
        float w2 = (float)(m2 >> 17) * qs, w3 = (float)(m3 >> 17) * qs;
        accx += w0 * lo_bf(v0) + w1 * lo_bf(v1) + w2 * lo_bf(v2) + w3 * lo_bf(v3);
        accy += w0 * hi_bf(v0) + w1 * hi_bf(v1) + w2 * hi_bf(v2) + w3 * hi_bf(v3);
    }
    for (; p < end; p += 2) {
        u32 m = csr4[p];
        u32 v = X2[(size_t)(m & 0x1FFFFu) * 32 + fi];
        float w = (float)(m >> 17) * qs;
        accx += w * lo_bf(v); accy += w * hi_bf(v);
    }
    accx += __shfl_xor(accx, 32);
    accy += __shfl_xor(accy, 32);
    if (half == 0) {
        accx *= dv; accy *= dv;
        u32 pack = ((u32)bfbits(accy) << 16) | (u32)bfbits(accx);
        ((u32*)G)[(size_t)node * 32 + fi] = pack;
    }
}

// ---------------- fused tail: pool + tabular MLP + head + sigmoid ----------
// one block (256 threads) per graph
__global__ __launch_bounds__(256) void tail_k(const u16* __restrict__ A,
        const int* __restrict__ batch, const void* __restrict__ x_tab,
        const float* __restrict__ Wt1, const float* __restrict__ bt1,
        const float* __restrict__ Wt2, const float* __restrict__ bt2,
        const float* __restrict__ Wf1, const float* __restrict__ bf1,
        const float* __restrict__ Wf2, const float* __restrict__ bf2,
        const float* __restrict__ Wf3, const float* __restrict__ bf3,
        void* __restrict__ out, const int* __restrict__ flagp)
{
    __shared__ float xs[384];    // [mean(128) | max(128) | tab(128)]
    __shared__ float t1s[256];
    __shared__ float u1s[256];
    __shared__ float u2s[128];
    __shared__ float xts[200];
    __shared__ float ps[256], pm[256];
    __shared__ int sb[2];
    int g = blockIdx.x;
    int tid = threadIdx.x;
    if (tid == 0) {
        int lo = 0, hi = N_NODES;
        while (lo < hi) { int m = (lo + hi) >> 1; if (batch[m] < g) lo = m + 1; else hi = m; }
        sb[0] = lo;
        hi = N_NODES;
        while (lo < hi) { int m = (lo + hi) >> 1; if (batch[m] < g + 1) lo = m + 1; else hi = m; }
        sb[1] = lo;
    }
    int isb = *flagp;
    if (tid < 200)
        xts[tid] = isb ? b2f(((const bf16*)x_tab)[(size_t)g * 200 + tid])
                       : ((const float*)x_tab)[(size_t)g * 200 + tid];
    __syncthreads();
    int start = sb[0], end = sb[1];
    // pool: 2 halves x 128 features
    int t = tid & 127, half = tid >> 7;
    float sum = 0.f, mx = -3.4e38f;
    for (int n = start + half; n < end; n += 2) {
        float v = __uint_as_float(((u32)A[(size_t)n * 128 + t]) << 16);
        sum += v; mx = fmaxf(mx, v);
    }
    ps[tid] = sum; pm[tid] = mx;
    __syncthreads();
    if (half == 0) {
        int c = end - start;
        float s2 = ps[t] + ps[t + 128];
        float m2 = fmaxf(pm[t], pm[t + 128]);
        xs[t] = s2 / (float)(c > 0 ? c : 1);
        xs[128 + t] = (c > 0) ? m2 : 0.f;
    }
    // tabular layer 1: 256 cols
    float acc = bt1[tid];
    for (int k = 0; k < 200; ++k) acc += xts[k] * Wt1[k * 256 + tid];
    t1s[tid] = fmaxf(acc, 0.f);
    __syncthreads();
    // tabular layer 2: 128 cols -> xs[256..384]
    if (tid < 128) {
        acc = bt2[tid];
        for (int k = 0; k < 256; ++k) acc += t1s[k] * Wt2[k * 128 + tid];
        xs[256 + tid] = fmaxf(acc, 0.f);
    }
    __syncthreads();
    // head layer 1: 256 cols
    acc = bf1[tid];
    for (int k = 0; k < 384; ++k) acc += xs[k] * Wf1[k * 256 + tid];
    u1s[tid] = fmaxf(acc, 0.f);
    __syncthreads();
    // head layer 2: 128 cols
    if (tid < 128) {
        acc = bf2[tid];
        for (int k = 0; k < 256; ++k) acc += u1s[k] * Wf2[k * 128 + tid];
        u2s[tid] = fmaxf(acc, 0.f);
    }
    __syncthreads();
    // head layer 3 + sigmoid (first wave)
    if (tid < 64) {
        float a = u2s[tid] * Wf3[tid] + u2s[tid + 64] * Wf3[tid + 64];
        for (int off = 32; off > 0; off >>= 1) a += __shfl_down(a, off);
        if (tid == 0) {
            float z = a + bf3[0];
            float sg = 1.f / (1.f + expf(-z));
            if (isb) ((bf16*)out)[g] = __float2bfloat16(sg);
            else     ((float*)out)[g] = sg;
        }
    }
}

extern "C" void kernel_launch(void* const* d_in, const int* in_sizes, int n_in,
                              void* d_out, int out_size, void* d_ws, size_t ws_size,
                              hipStream_t stream) {
    const void* x_graph    = d_in[0];
    const int*  edge_index = (const int*)d_in[1];
    const int*  batch      = (const int*)d_in[2];
    const void* x_tab      = d_in[3];

    const int* src  = edge_index;
    const int* dstp = edge_index + N_EDGES;

    // ---------------- workspace layout ----------------
    char* wsp = (char*)d_ws;
    int*  flag = (int*)wsp;                      wsp += 16;
    u16*  A16  = (u16*)wsp;                      wsp += (size_t)N_NODES * 128 * 2;
    u16*  B16  = (u16*)wsp;                      wsp += (size_t)N_NODES * 128 * 2;
    u16*  X16  = (u16*)wsp;                      wsp += (size_t)N_NODES * 64 * 2;
    u16*  G16  = (u16*)wsp;                      wsp += (size_t)N_NODES * 64 * 2;
    u16*  Wm[4];
    Wm[0] = (u16*)wsp;                           wsp += 64 * 128 * 2;
    Wm[1] = (u16*)wsp;                           wsp += 128 * 128 * 2;
    Wm[2] = (u16*)wsp;                           wsp += 128 * 128 * 2;
    Wm[3] = (u16*)wsp;                           wsp += 128 * 128 * 2;
    float* p = (float*)wsp;
    float* bg1f = p; p += 128;
    float* bg2f = p; p += 128;
    float* bg3f = p; p += 128;
    float* bg4f = p; p += 128;
    float* Wt1f = p; p += 200 * 256; float* bt1f = p; p += 256;
    float* Wt2f = p; p += 256 * 128; float* bt2f = p; p += 128;
    float* Wf1f = p; p += 384 * 256; float* bf1f = p; p += 256;
    float* Wf2f = p; p += 256 * 128; float* bf2f = p; p += 128;
    float* Wf3f = p; p += 128;       float* bf3f = p; p += 4;
    int*   degi   = (int*)p;            p += N_NODES;
    float* dinv   = p;                  p += N_NODES;
    int*   rowptr = (int*)p;            p += N_NODES;
    int*   cnt    = (int*)p;            p += N_NODES;
    int*   bsum   = (int*)p;            p += 512;
    u32*   csr4   = (u32*)p;            p += N_EDGES;

    // ---------------- sniff + degi init ----------------
    sniff_init<<<(N_NODES + 255) / 256, 256, 0, stream>>>((const u16*)x_graph, flag, degi);

    // ---------------- fused prep (weights + x_graph) ----------------
    PrepArgs pa;
    auto setT = [&](int i, const void* s, void* d, int n, int mode) {
        pa.t[i].src = s; pa.t[i].dst = d; pa.t[i].n = n; pa.t[i].mode = mode;
    };
    setT(0,  d_in[4],  Wm[0], 64 * 128, 1);
    setT(1,  d_in[6],  Wm[1], 128 * 128, 1);
    setT(2,  d_in[8],  Wm[2], 128 * 128, 1);
    setT(3,  d_in[10], Wm[3], 128 * 128, 1);
    setT(4,  d_in[12], Wt1f, 200 * 256, 0);
    setT(5,  d_in[14], Wt2f, 256 * 128, 0);
    setT(6,  d_in[16], Wf1f, 384 * 256, 0);
    setT(7,  d_in[18], Wf2f, 256 * 128, 0);
    setT(8,  d_in[20], Wf3f, 128, 0);
    setT(9,  d_in[5],  bg1f, 128, 0);
    setT(10, d_in[7],  bg2f, 128, 0);
    setT(11, d_in[9],  bg3f, 128, 0);
    setT(12, d_in[11], bg4f, 128, 0);
    setT(13, d_in[13], bt1f, 256, 0);
    setT(14, d_in[15], bt2f, 128, 0);
    setT(15, d_in[17], bf1f, 256, 0);
    setT(16, d_in[19], bf2f, 128, 0);
    setT(17, d_in[21], bf3f, 1, 0);
    setT(18, d_in[0],  X16, N_NODES * 64, 2);
    int totalBlocks = 0;
    for (int i = 0; i < NT; ++i) {
        pa.bstart[i] = totalBlocks;
        totalBlocks += (pa.t[i].n + 255) / 256;
    }
    prep_k<<<totalBlocks, 256, 0, stream>>>(pa, flag);

    // ---------------- degree / norm / CSR ----------------
    const int nb = (N_NODES + SCAN_B - 1) / SCAN_B;   // 391
    deg_edges<<<(N_EDGES + 255) / 256, 256, 0, stream>>>(dstp, degi);
    scan1<<<nb, SCAN_B, 0, stream>>>(degi, rowptr, bsum, dinv);
    scan2<<<1, 512, 0, stream>>>(bsum, nb);
    scan3<<<nb, SCAN_B, 0, stream>>>(rowptr, bsum, cnt);
    fill_csr<<<(N_EDGES + 255) / 256, 256, 0, stream>>>(src, dstp, dinv, rowptr, cnt, csr4);

    const int gemmGrid = (N_NODES + 63) / 64;   // 1563
    const int aggGrid  = (N_NODES + 3) / 4;     // 25000

    // ---- layer 1 (reassociated): G = A_hat X ; A = relu(G W1 + b1) ----
    gather_x<<<aggGrid, 256, 0, stream>>>(rowptr, cnt, csr4, X16, dinv, G16);
    gemm_mfma<64, true><<<gemmGrid, 256, 0, stream>>>(G16, Wm[0], bg1f, A16, N_NODES);

    // ---- layers 2-4: B = A W_l ; A = relu(agg(B) + b_l) ----
    const float* bgL[4] = {bg1f, bg2f, bg3f, bg4f};
    for (int l = 1; l < 4; ++l) {
        gemm_mfma<128, false><<<gemmGrid, 256, 0, stream>>>(A16, Wm[l], nullptr, B16, N_NODES);
        gather_agg<<<aggGrid, 256, 0, stream>>>(rowptr, cnt, csr4, B16, dinv, bgL[l], A16);
    }

    // ---- fused tail: pool + tabular + head ----
    tail_k<<<N_GRAPHS, 256, 0, stream>>>(A16, batch, x_tab,
        Wt1f, bt1f, Wt2f, bt2f, Wf1f, bf1f, Wf2f, bf2f, Wf3f, bf3f, d_out, flag);
}

// Round 8
// 628.221 us; speedup vs baseline: 2.1558x; 1.1674x over previous
//
#include <hip/hip_runtime.h>
#include <hip/hip_bf16.h>
#include <math.h>

#define N_NODES  100000
#define N_EDGES  1600000
#define N_GRAPHS 1024
#define NBUCK    391        // buckets of 256 nodes (dst >> 8)
#define BPAD     5120       // padded entries per bucket (expect ~4082, +16 sigma)

typedef __hip_bfloat16 bf16;
typedef unsigned short u16;
typedef unsigned int   u32;
typedef __attribute__((ext_vector_type(8))) short bf8_t;   // 8 bf16 (4 VGPRs)
typedef __attribute__((ext_vector_type(4))) float f4_t;    // 4 fp32 acc

__device__ __forceinline__ float b2f(bf16 v) { return __bfloat162float(v); }
__device__ __forceinline__ u16 bfbits(float f) {
    bf16 h = __float2bfloat16(f);
    return *reinterpret_cast<u16*>(&h);
}
__device__ __forceinline__ float lo_bf(u32 u) { return __uint_as_float(u << 16); }
__device__ __forceinline__ float hi_bf(u32 u) { return __uint_as_float(u & 0xffff0000u); }

// ---------------- sniff dtype + zero bucket counters ----------------
__global__ void sniff_k(const u16* __restrict__ xg, int* __restrict__ flag,
                        int* __restrict__ gbucket) {
    int tid = threadIdx.x;
    if (tid < NBUCK) gbucket[tid] = 0;
    if (tid == 511) {
        int bad = 0;
        for (int k = 0; k < 256; ++k) {
            float f = __uint_as_float(((u32)xg[k]) << 16);
            if (!(fabsf(f) < 100.f)) bad++;
        }
        *flag = (bad == 0) ? 1 : 0;
    }
}

// ---------------- fused prep: cvt->fp32 / repack->MFMA bf16 / cvt->bf16 ---
#define NT 19
struct WTask { const void* src; void* dst; int n; int mode; };
struct PrepArgs { WTask t[NT]; int bstart[NT]; };

__global__ void prep_k(PrepArgs args, const int* __restrict__ flag) {
    int b = blockIdx.x, ti = 0;
    while (ti < NT - 1 && b >= args.bstart[ti + 1]) ++ti;
    int idx = (b - args.bstart[ti]) * 256 + threadIdx.x;
    WTask tk = args.t[ti];
    if (idx >= tk.n) return;
    int isb = *flag;
    if (tk.mode == 0) {
        float v = isb ? b2f(((const bf16*)tk.src)[idx]) : ((const float*)tk.src)[idx];
        ((float*)tk.dst)[idx] = v;
    } else if (tk.mode == 1) {
        // MFMA B-frag layout: element = W[kb*32+(L>>4)*8+j][t*16+(L&15)]
        int bseg = idx >> 9, r = idx & 511;
        int L = r >> 3, j = r & 7;
        int kb = bseg >> 3, tt = bseg & 7;
        int k = kb * 32 + ((L >> 4) << 3) + j;
        int n = (tt << 4) + (L & 15);
        int so = k * 128 + n;
        float v = isb ? b2f(((const bf16*)tk.src)[so]) : ((const float*)tk.src)[so];
        ((u16*)tk.dst)[idx] = bfbits(v);
    } else {
        // plain bf16 copy (row-major)
        u16 v = isb ? ((const u16*)tk.src)[idx] : bfbits(((const float*)tk.src)[idx]);
        ((u16*)tk.dst)[idx] = v;
    }
}

// ---------------- pass A: bin edges by dst>>8 into padded regions --------
// staged entry: (dst&255)<<17 | src   (4 bytes)
#define BIN_CH 4093
__global__ __launch_bounds__(256) void bin_a(const int* __restrict__ src,
        const int* __restrict__ dst, int* __restrict__ gbucket,
        u32* __restrict__ st) {
    __shared__ int hist[NBUCK];
    __shared__ int bas[NBUCK];
    int b = blockIdx.x, tid = threadIdx.x;
    for (int j = tid; j < NBUCK; j += 256) hist[j] = 0;
    __syncthreads();
    int e0 = b * BIN_CH;
    int eend = e0 + BIN_CH; if (eend > N_EDGES) eend = N_EDGES;
    for (int e = e0 + tid; e < eend; e += 256)
        atomicAdd(&hist[dst[e] >> 8], 1);
    __syncthreads();
    for (int j = tid; j < NBUCK; j += 256) {
        int c = hist[j];
        bas[j] = c ? atomicAdd(&gbucket[j], c) : 0;
        hist[j] = 0;
    }
    __syncthreads();
    for (int e = e0 + tid; e < eend; e += 256) {
        int d = dst[e], s = src[e];
        int bk = d >> 8;
        int idx = atomicAdd(&hist[bk], 1);
        st[(size_t)bk * BPAD + bas[bk] + idx] = ((u32)(d & 255) << 17) | (u32)s;
    }
}

// ---------------- pass B1: per-bucket node histogram -> rowptr/cnt/dinv/qd -
__global__ __launch_bounds__(256) void b1_nodes(const int* __restrict__ gbucket,
        const u32* __restrict__ st, int* __restrict__ rowptr,
        int* __restrict__ cnt, float* __restrict__ dinv, u16* __restrict__ qd) {
    __shared__ int nh[256];
    __shared__ int s[256];
    int b = blockIdx.x, tid = threadIdx.x;
    nh[tid] = 0;
    __syncthreads();
    int cb = gbucket[b];
    const u32* stb = st + (size_t)b * BPAD;
    for (int i = tid; i < cb; i += 256)
        atomicAdd(&nh[(stb[i] >> 17) & 255], 1);
    __syncthreads();
    int own = nh[tid];
    s[tid] = own;
    __syncthreads();
    for (int off = 1; off < 256; off <<= 1) {
        int t = (tid >= off) ? s[tid - off] : 0;
        __syncthreads();
        if (tid >= off) s[tid] += t;
        __syncthreads();
    }
    int ex = s[tid] - own;
    int n = b * 256 + tid;
    if (n < N_NODES) {
        rowptr[n] = b * BPAD + ex;
        cnt[n] = own;
        float dv = rsqrtf((float)(own + 2));
        dinv[n] = dv;
        qd[n] = (u16)__float2int_rn(dv * 32767.f);
    }
}

// ---------------- pass B2: per-bucket local scatter into csr4 -------------
// csr4 entry: q15(dinv_src) << 17 | src
__global__ __launch_bounds__(256) void b2_scatter(const int* __restrict__ gbucket,
        const u32* __restrict__ st, const int* __restrict__ rowptr,
        const u16* __restrict__ qd, u32* __restrict__ csr4) {
    __shared__ int rp[256];
    __shared__ int lc[256];
    int b = blockIdx.x, tid = threadIdx.x;
    int n = b * 256 + tid;
    rp[tid] = (n < N_NODES) ? rowptr[n] : 0;
    lc[tid] = 0;
    __syncthreads();
    int cb = gbucket[b];
    const u32* stb = st + (size_t)b * BPAD;
    for (int i = tid; i < cb; i += 256) {
        u32 v = stb[i];
        int ld = (v >> 17) & 255;
        u32 sidx = v & 0x1FFFFu;
        int idx = atomicAdd(&lc[ld], 1);
        csr4[rp[ld] + idx] = ((u32)qd[sidx] << 17) | sidx;
    }
}

// ---------------- MFMA GEMM: Out[M x 128](bf16) = A[M x K](bf16) @ W ----
template<int K, bool EPI>
__global__ __launch_bounds__(256) void gemm_mfma(const u16* __restrict__ A,
        const u16* __restrict__ Wm, const float* __restrict__ bias,
        u16* __restrict__ Out, int M)
{
    int wave = threadIdx.x >> 6, lane = threadIdx.x & 63;
    int rowBase = blockIdx.x * 64 + wave * 16;
    int quad = lane >> 4, low = lane & 15;
    int arow = rowBase + low;
    if (arow >= M) arow = M - 1;
    const u16* ap = A + (size_t)arow * K + quad * 8;

    f4_t acc[8];
#pragma unroll
    for (int t = 0; t < 8; ++t) acc[t] = (f4_t)(0.f);

#pragma unroll
    for (int kb = 0; kb < K / 32; ++kb) {
        bf8_t a = *(const bf8_t*)(ap + kb * 32);
#pragma unroll
        for (int t = 0; t < 8; ++t) {
            bf8_t b = *(const bf8_t*)(Wm + (((kb << 3) + t) << 9) + lane * 8);
            acc[t] = __builtin_amdgcn_mfma_f32_16x16x32_bf16(a, b, acc[t], 0, 0, 0);
        }
    }

    int orow0 = rowBase + quad * 4;
#pragma unroll
    for (int t = 0; t < 8; ++t) {
        float bn = EPI ? bias[t * 16 + low] : 0.f;
#pragma unroll
        for (int j = 0; j < 4; ++j) {
            int r = orow0 + j;
            float v = acc[t][j];
            if (EPI) v = fmaxf(v + bn, 0.f);
            if (r < M) Out[(size_t)r * 128 + t * 16 + low] = bfbits(v);
        }
    }
}

// ---------------- gather (128-wide H) ----------------
__global__ __launch_bounds__(256) void gather_agg(
        const int* __restrict__ rowptr, const int* __restrict__ cnt,
        const u32* __restrict__ csr4, const u16* __restrict__ H,
        const float* __restrict__ dinv, const float* __restrict__ bias,
        u16* __restrict__ A)
{
    int node = blockIdx.x * 4 + (threadIdx.x >> 6);
    if (node >= N_NODES) return;
    int lane = threadIdx.x & 63;
    const u32* H2 = (const u32*)H;
    float2 bb = ((const float2*)bias)[lane];
    float dv = dinv[node];
    u32 h0 = H2[(size_t)node * 64 + lane];
    float accx = 2.f * dv * lo_bf(h0);
    float accy = 2.f * dv * hi_bf(h0);
    int p = rowptr[node];
    int end = p + cnt[node];
    const float qs = 1.f / 32767.f;
    for (; p + 8 <= end; p += 8) {
        u32 m0 = csr4[p],     m1 = csr4[p + 1];
        u32 m2 = csr4[p + 2], m3 = csr4[p + 3];
        u32 m4 = csr4[p + 4], m5 = csr4[p + 5];
        u32 m6 = csr4[p + 6], m7 = csr4[p + 7];
        u32 v0 = H2[(size_t)(m0 & 0x1FFFFu) * 64 + lane];
        u32 v1 = H2[(size_t)(m1 & 0x1FFFFu) * 64 + lane];
        u32 v2 = H2[(size_t)(m2 & 0x1FFFFu) * 64 + lane];
        u32 v3 = H2[(size_t)(m3 & 0x1FFFFu) * 64 + lane];
        u32 v4 = H2[(size_t)(m4 & 0x1FFFFu) * 64 + lane];
        u32 v5 = H2[(size_t)(m5 & 0x1FFFFu) * 64 + lane];
        u32 v6 = H2[(size_t)(m6 & 0x1FFFFu) * 64 + lane];
        u32 v7 = H2[(size_t)(m7 & 0x1FFFFu) * 64 + lane];
        float w0 = (float)(m0 >> 17) * qs, w1 = (float)(m1 >> 17) * qs;
        float w2 = (float)(m2 >> 17) * qs, w3 = (float)(m3 >> 17) * qs;
        float w4 = (float)(m4 >> 17) * qs, w5 = (float)(m5 >> 17) * qs;
        float w6 = (float)(m6 >> 17) * qs, w7 = (float)(m7 >> 17) * qs;
        accx += w0 * lo_bf(v0) + w1 * lo_bf(v1) + w2 * lo_bf(v2) + w3 * lo_bf(v3)
              + w4 * lo_bf(v4) + w5 * lo_bf(v5) + w6 * lo_bf(v6) + w7 * lo_bf(v7);
        accy += w0 * hi_bf(v0) + w1 * hi_bf(v1) + w2 * hi_bf(v2) + w3 * hi_bf(v3)
              + w4 * hi_bf(v4) + w5 * hi_bf(v5) + w6 * hi_bf(v6) + w7 * hi_bf(v7);
    }
    for (; p < end; ++p) {
        u32 m = csr4[p];
        u32 v = H2[(size_t)(m & 0x1FFFFu) * 64 + lane];
        float w = (float)(m >> 17) * qs;
        accx += w * lo_bf(v); accy += w * hi_bf(v);
    }
    accx = fmaxf(accx * dv + bb.x, 0.f);
    accy = fmaxf(accy * dv + bb.y, 0.f);
    u32 pack = ((u32)bfbits(accy) << 16) | (u32)bfbits(accx);
    ((u32*)A)[(size_t)node * 64 + lane] = pack;
}

// ---------------- layer-1 gather on 64-wide X ----------------
__global__ __launch_bounds__(256) void gather_x(
        const int* __restrict__ rowptr, const int* __restrict__ cnt,
        const u32* __restrict__ csr4, const u16* __restrict__ X,
        const float* __restrict__ dinv, u16* __restrict__ G)
{
    int node = blockIdx.x * 4 + (threadIdx.x >> 6);
    if (node >= N_NODES) return;
    int lane = threadIdx.x & 63;
    int half = lane >> 5, fi = lane & 31;
    const u32* X2 = (const u32*)X;   // 32 u32 per row
    float dv = dinv[node];
    float accx = 0.f, accy = 0.f;
    if (half == 0) {
        u32 h0 = X2[(size_t)node * 32 + fi];
        accx = 2.f * dv * lo_bf(h0); accy = 2.f * dv * hi_bf(h0);
    }
    int rp = rowptr[node];
    int end = rp + cnt[node];
    const float qs = 1.f / 32767.f;
    int p = rp + half;
    for (; p + 6 < end; p += 8) {
        u32 m0 = csr4[p],     m1 = csr4[p + 2];
        u32 m2 = csr4[p + 4], m3 = csr4[p + 6];
        u32 v0 = X2[(size_t)(m0 & 0x1FFFFu) * 32 + fi];
        u32 v1 = X2[(size_t)(m1 & 0x1FFFFu) * 32 + fi];
        u32 v2 = X2[(size_t)(m2 & 0x1FFFFu) * 32 + fi];
        u32 v3 = X2[(size_t)(m3 & 0x1FFFFu) * 32 + fi];
        float w0 = (float)(m0 >> 17) * qs, w1 = (float)(m1 >> 17) * qs;
        float w2 = (float)(m2 >> 17) * qs, w3 = (float)(m3 >> 17) * qs;
        accx += w0 * lo_bf(v0) + w1 * lo_bf(v1) + w2 * lo_bf(v2) + w3 * lo_bf(v3);
        accy += w0 * hi_bf(v0) + w1 * hi_bf(v1) + w2 * hi_bf(v2) + w3 * hi_bf(v3);
    }
    for (; p < end; p += 2) {
        u32 m = csr4[p];
        u32 v = X2[(size_t)(m & 0x1FFFFu) * 32 + fi];
        float w = (float)(m >> 17) * qs;
        accx += w * lo_bf(v); accy += w * hi_bf(v);
    }
    accx += __shfl_xor(accx, 32);
    accy += __shfl_xor(accy, 32);
    if (half == 0) {
        accx *= dv; accy *= dv;
        u32 pack = ((u32)bfbits(accy) << 16) | (u32)bfbits(accx);
        ((u32*)G)[(size_t)node * 32 + fi] = pack;
    }
}

// ---------------- fused tail: pool + tabular MLP + head + sigmoid ----------
__global__ __launch_bounds__(256) void tail_k(const u16* __restrict__ A,
        const int* __restrict__ batch, const void* __restrict__ x_tab,
        const float* __restrict__ Wt1, const float* __restrict__ bt1,
        const float* __restrict__ Wt2, const float* __restrict__ bt2,
        const float* __restrict__ Wf1, const float* __restrict__ bf1,
        const float* __restrict__ Wf2, const float* __restrict__ bf2,
        const float* __restrict__ Wf3, const float* __restrict__ bf3,
        void* __restrict__ out, const int* __restrict__ flagp)
{
    __shared__ float xs[384];    // [mean(128) | max(128) | tab(128)]
    __shared__ float t1s[256];
    __shared__ float u1s[256];
    __shared__ float u2s[128];
    __shared__ float xts[200];
    __shared__ float ps[256], pm[256];
    __shared__ int sb[2];
    int g = blockIdx.x;
    int tid = threadIdx.x;
    if (tid == 0) {
        int lo = 0, hi = N_NODES;
        while (lo < hi) { int m = (lo + hi) >> 1; if (batch[m] < g) lo = m + 1; else hi = m; }
        sb[0] = lo;
        hi = N_NODES;
        while (lo < hi) { int m = (lo + hi) >> 1; if (batch[m] < g + 1) lo = m + 1; else hi = m; }
        sb[1] = lo;
    }
    int isb = *flagp;
    if (tid < 200)
        xts[tid] = isb ? b2f(((const bf16*)x_tab)[(size_t)g * 200 + tid])
                       : ((const float*)x_tab)[(size_t)g * 200 + tid];
    __syncthreads();
    int start = sb[0], end = sb[1];
    int t = tid & 127, half = tid >> 7;
    float sum = 0.f, mx = -3.4e38f;
    for (int n = start + half; n < end; n += 2) {
        float v = __uint_as_float(((u32)A[(size_t)n * 128 + t]) << 16);
        sum += v; mx = fmaxf(mx, v);
    }
    ps[tid] = sum; pm[tid] = mx;
    __syncthreads();
    if (half == 0) {
        int c = end - start;
        float s2 = ps[t] + ps[t + 128];
        float m2 = fmaxf(pm[t], pm[t + 128]);
        xs[t] = s2 / (float)(c > 0 ? c : 1);
        xs[128 + t] = (c > 0) ? m2 : 0.f;
    }
    float acc = bt1[tid];
    for (int k = 0; k < 200; ++k) acc += xts[k] * Wt1[k * 256 + tid];
    t1s[tid] = fmaxf(acc, 0.f);
    __syncthreads();
    if (tid < 128) {
        acc = bt2[tid];
        for (int k = 0; k < 256; ++k) acc += t1s[k] * Wt2[k * 128 + tid];
        xs[256 + tid] = fmaxf(acc, 0.f);
    }
    __syncthreads();
    acc = bf1[tid];
    for (int k = 0; k < 384; ++k) acc += xs[k] * Wf1[k * 256 + tid];
    u1s[tid] = fmaxf(acc, 0.f);
    __syncthreads();
    if (tid < 128) {
        acc = bf2[tid];
        for (int k = 0; k < 256; ++k) acc += u1s[k] * Wf2[k * 128 + tid];
        u2s[tid] = fmaxf(acc, 0.f);
    }
    __syncthreads();
    if (tid < 64) {
        float a = u2s[tid] * Wf3[tid] + u2s[tid + 64] * Wf3[tid + 64];
        for (int off = 32; off > 0; off >>= 1) a += __shfl_down(a, off);
        if (tid == 0) {
            float z = a + bf3[0];
            float sg = 1.f / (1.f + expf(-z));
            if (isb) ((bf16*)out)[g] = __float2bfloat16(sg);
            else     ((float*)out)[g] = sg;
        }
    }
}

extern "C" void kernel_launch(void* const* d_in, const int* in_sizes, int n_in,
                              void* d_out, int out_size, void* d_ws, size_t ws_size,
                              hipStream_t stream) {
    const void* x_graph    = d_in[0];
    const int*  edge_index = (const int*)d_in[1];
    const int*  batch      = (const int*)d_in[2];
    const void* x_tab      = d_in[3];

    const int* src  = edge_index;
    const int* dstp = edge_index + N_EDGES;

    // ---------------- workspace layout ----------------
    char* wsp = (char*)d_ws;
    int*  flag = (int*)wsp;                      wsp += 16;
    u16*  A16  = (u16*)wsp;                      wsp += (size_t)N_NODES * 128 * 2;
    u16*  B16  = (u16*)wsp;                      wsp += (size_t)N_NODES * 128 * 2;
    u16*  X16  = (u16*)wsp;                      wsp += (size_t)N_NODES * 64 * 2;
    u16*  G16  = (u16*)wsp;                      wsp += (size_t)N_NODES * 64 * 2;
    u16*  Wm[4];
    Wm[0] = (u16*)wsp;                           wsp += 64 * 128 * 2;
    Wm[1] = (u16*)wsp;                           wsp += 128 * 128 * 2;
    Wm[2] = (u16*)wsp;                           wsp += 128 * 128 * 2;
    Wm[3] = (u16*)wsp;                           wsp += 128 * 128 * 2;
    float* p = (float*)wsp;
    float* bg1f = p; p += 128;
    float* bg2f = p; p += 128;
    float* bg3f = p; p += 128;
    float* bg4f = p; p += 128;
    float* Wt1f = p; p += 200 * 256; float* bt1f = p; p += 256;
    float* Wt2f = p; p += 256 * 128; float* bt2f = p; p += 128;
    float* Wf1f = p; p += 384 * 256; float* bf1f = p; p += 256;
    float* Wf2f = p; p += 256 * 128; float* bf2f = p; p += 128;
    float* Wf3f = p; p += 128;       float* bf3f = p; p += 4;
    float* dinv   = p;                  p += N_NODES;
    int*   rowptr = (int*)p;            p += N_NODES;
    int*   cnt    = (int*)p;            p += N_NODES;
    u16*   qd     = (u16*)p;            p += (N_NODES + 1) / 2;
    int*   gbucket= (int*)p;            p += 512;
    u32*   st     = (u32*)p;            p += (size_t)NBUCK * BPAD;
    u32*   csr4   = (u32*)p;            p += (size_t)NBUCK * BPAD;

    // ---------------- sniff + zero bucket counters ----------------
    sniff_k<<<1, 512, 0, stream>>>((const u16*)x_graph, flag, gbucket);

    // ---------------- fused prep (weights + x_graph) ----------------
    PrepArgs pa;
    auto setT = [&](int i, const void* s, void* d, int n, int mode) {
        pa.t[i].src = s; pa.t[i].dst = d; pa.t[i].n = n; pa.t[i].mode = mode;
    };
    setT(0,  d_in[4],  Wm[0], 64 * 128, 1);
    setT(1,  d_in[6],  Wm[1], 128 * 128, 1);
    setT(2,  d_in[8],  Wm[2], 128 * 128, 1);
    setT(3,  d_in[10], Wm[3], 128 * 128, 1);
    setT(4,  d_in[12], Wt1f, 200 * 256, 0);
    setT(5,  d_in[14], Wt2f, 256 * 128, 0);
    setT(6,  d_in[16], Wf1f, 384 * 256, 0);
    setT(7,  d_in[18], Wf2f, 256 * 128, 0);
    setT(8,  d_in[20], Wf3f, 128, 0);
    setT(9,  d_in[5],  bg1f, 128, 0);
    setT(10, d_in[7],  bg2f, 128, 0);
    setT(11, d_in[9],  bg3f, 128, 0);
    setT(12, d_in[11], bg4f, 128, 0);
    setT(13, d_in[13], bt1f, 256, 0);
    setT(14, d_in[15], bt2f, 128, 0);
    setT(15, d_in[17], bf1f, 256, 0);
    setT(16, d_in[19], bf2f, 128, 0);
    setT(17, d_in[21], bf3f, 1, 0);
    setT(18, d_in[0],  X16, N_NODES * 64, 2);
    int totalBlocks = 0;
    for (int i = 0; i < NT; ++i) {
        pa.bstart[i] = totalBlocks;
        totalBlocks += (pa.t[i].n + 255) / 256;
    }
    prep_k<<<totalBlocks, 256, 0, stream>>>(pa, flag);

    // ---------------- CSR build: bin -> node meta -> local scatter --------
    bin_a<<<NBUCK, 256, 0, stream>>>(src, dstp, gbucket, st);
    b1_nodes<<<NBUCK, 256, 0, stream>>>(gbucket, st, rowptr, cnt, dinv, qd);
    b2_scatter<<<NBUCK, 256, 0, stream>>>(gbucket, st, rowptr, qd, csr4);

    const int gemmGrid = (N_NODES + 63) / 64;   // 1563
    const int aggGrid  = (N_NODES + 3) / 4;     // 25000

    // ---- layer 1 (reassociated): G = A_hat X ; A = relu(G W1 + b1) ----
    gather_x<<<aggGrid, 256, 0, stream>>>(rowptr, cnt, csr4, X16, dinv, G16);
    gemm_mfma<64, true><<<gemmGrid, 256, 0, stream>>>(G16, Wm[0], bg1f, A16, N_NODES);

    // ---- layers 2-4: B = A W_l ; A = relu(agg(B) + b_l) ----
    const float* bgL[4] = {bg1f, bg2f, bg3f, bg4f};
    for (int l = 1; l < 4; ++l) {
        gemm_mfma<128, false><<<gemmGrid, 256, 0, stream>>>(A16, Wm[l], nullptr, B16, N_NODES);
        gather_agg<<<aggGrid, 256, 0, stream>>>(rowptr, cnt, csr4, B16, dinv, bgL[l], A16);
    }

    // ---- fused tail: pool + tabular + head ----
    tail_k<<<N_GRAPHS, 256, 0, stream>>>(A16, batch, x_tab,
        Wt1f, bt1f, Wt2f, bt2f, Wf1f, bf1f, Wf2f, bf2f, Wf3f, bf3f, d_out, flag);
}